// Round 11
// baseline (398.068 us; speedup 1.0000x reference)
//
#include <hip/hip_runtime.h>
#include <hip/hip_bf16.h>

#define NN 20000
#define NE 320000
#define NG 256
#define DD 256
#define NL 4
#define NBX2 157   // (NN+127)/128 gemm m-blocks
#define NBKT 79    // ceil(NN/256) scan buckets

typedef __attribute__((ext_vector_type(8))) short short8;
typedef __attribute__((ext_vector_type(4))) float float4_t;

// flags[0]=1 if edge_index int64; flags[1]=1 if batch int64; flags[2]=1 if floats bf16
__device__ __forceinline__ int ld_idx(const int* __restrict__ p, int i, int f64) {
    return f64 ? p[2 * i] : p[i];
}

__device__ __forceinline__ float bf2f(ushort u) {
    return __uint_as_float(((unsigned)u) << 16);
}

__device__ __forceinline__ ushort f2bf(float f) {
    __hip_bfloat16 b = __float2bfloat16(f);
    return *(ushort*)&b;
}

// ---------------- init: zero deg, dtype detection (block 0) ----

__global__ void k_init(const int* __restrict__ ei, const int* __restrict__ batch,
                       const ushort* __restrict__ x, int* __restrict__ flags,
                       int* __restrict__ deg) {
    int gid = blockIdx.x * 256 + threadIdx.x;
    for (int i = gid; i < NN; i += gridDim.x * 256) deg[i] = 0;
    if (blockIdx.x == 0) {
        __shared__ int cnt0, cnt1, weird;
        int t = threadIdx.x;
        if (t == 0) { cnt0 = 0; cnt1 = 0; weird = 0; }
        __syncthreads();
        for (int tt = t; tt < 512; tt += 256) {
            if (ei[2 * tt + 1] != 0) atomicAdd(&cnt0, 1);
            int i = tt * 9;
            if (batch[2 * i + 1] != 0) atomicAdd(&cnt1, 1);
#pragma unroll
            for (int j = 0; j < 16; j++) {
                ushort v = x[tt * 16 + j];
                if (((v >> 7) & 0xFF) >= 0xC0) atomicAdd(&weird, 1);
            }
        }
        __syncthreads();
        if (t == 0) {
            flags[0] = (cnt0 == 0) ? 1 : 0;
            flags[1] = (cnt1 == 0) ? 1 : 0;
            flags[2] = (weird == 0) ? 1 : 0;
        }
    }
}

// ---------------- fused prep: cvt8 | WtF frag-build | cvtp | degree | gstart ---

#define POFF_BL   0
#define POFF_GA   1024
#define POFF_BE   2048
#define POFF_F1W  3072
#define POFF_F1B  35840
#define POFF_F2W  35968
#define POFF_F2B  44160
#define POFF_F3W  44224
#define POFF_F3B  44864
#define PTOT      44874

#define NB_CVT8   2500            // NN*DD/8/256
#define NB_FRAG   2048            // 2*NL*65536/256
#define NB_CVTP   176             // ceil(PTOT/256)
#define NB_DEG    1250            // NE/256
#define NB_GST    79              // ceil(NN/256)
#define B_FRAG    (NB_CVT8)
#define B_CVTP    (B_FRAG + NB_FRAG)
#define B_DEG     (B_CVTP + NB_CVTP)
#define B_GST     (B_DEG + NB_DEG)
#define NB_PREP   (B_GST + NB_GST)

// WtF fragment layout (per 256x256 matrix, 65536 elems):
//   element (n,k) lives at  ((n>>4)*8 + (k>>5))*512 + ((n&15) + 16*((k>>3)&3))*8 + (k&7)
// so a wave's B-fragment load is base + lane*8 (lane-contiguous 16B -> coalesced).

__global__ __launch_bounds__(256) void k_prep(
    const void* __restrict__ x_in, const void* __restrict__ WL,
    const void* __restrict__ WR, const int* __restrict__ ei,
    const int* __restrict__ batch,
    const void* s0, const void* s1, const void* s2, const void* s3,
    const void* s4, const void* s5, const void* s6, const void* s7, const void* s8,
    ushort* __restrict__ xcan, ushort* __restrict__ wtL, ushort* __restrict__ wtR,
    ushort* __restrict__ pcan, int* __restrict__ deg, int* __restrict__ gstart,
    const int* __restrict__ fl) {
    int blk = blockIdx.x;
    int t = threadIdx.x;
    if (blk < B_FRAG) {
        // x canonicalization, 8 elems/lane
        int i = blk * 256 + t;
        if (fl[2]) {
            *(int4*)(xcan + (size_t)i * 8) = ((const int4*)x_in)[i];
        } else {
            const float* f = (const float*)x_in + (size_t)i * 8;
            ushort ov[8];
#pragma unroll
            for (int d = 0; d < 8; d++) ov[d] = f2bf(f[d]);
            *(int4*)(xcan + (size_t)i * 8) = *(int4*)ov;
        }
    } else if (blk < B_CVTP) {
        // B-fragment layout build for Wl, Wr
        int idx = (blk - B_FRAG) * 256 + t;    // 0 .. 2*NL*65536-1
        int half = idx >> 18;                   // 0 -> L, 1 -> R
        int id = idx & 0x3FFFF;                 // matrix l * 65536 + within
        int within = id & 0xFFFF;
        int lmat = id >> 16;
        int fblk = within >> 9;                 // (n>>4)*8 + (k>>5)
        int lane = (within >> 3) & 63;
        int e = within & 7;
        int n = (fblk >> 3) * 16 + (lane & 15);
        int k = (fblk & 7) * 32 + (lane >> 4) * 8 + e;
        const void* W = half ? WR : WL;
        ushort* Wt = half ? wtR : wtL;
        size_t src = ((size_t)lmat << 16) + (k << 8) + n;
        Wt[id] = fl[2] ? ((const ushort*)W)[src] : f2bf(((const float*)W)[src]);
    } else if (blk < B_DEG) {
        // small params
        int i = (blk - B_CVTP) * 256 + t;
        if (i >= PTOT) return;
        const int offs[10] = {POFF_BL, POFF_GA, POFF_BE, POFF_F1W, POFF_F1B,
                              POFF_F2W, POFF_F2B, POFF_F3W, POFF_F3B, PTOT};
        const void* srcs[9] = {s0, s1, s2, s3, s4, s5, s6, s7, s8};
        int seg = 0;
#pragma unroll
        for (int k = 1; k < 9; k++) if (i >= offs[k]) seg = k;
        int local = i - offs[seg];
        if (fl[2]) pcan[i] = ((const ushort*)srcs[seg])[local];
        else       pcan[i] = f2bf(((const float*)srcs[seg])[local]);
    } else if (blk < B_GST) {
        // degree
        int e = (blk - B_DEG) * 256 + t;
        if (e < NE) {
            int src = ld_idx(ei, e, fl[0]);
            int dst = ld_idx(ei, NE + e, fl[0]);
            if ((unsigned)dst < NN && (unsigned)src < NN) atomicAdd(&deg[dst], 1);
        }
    } else {
        // gstart
        int i = (blk - B_GST) * 256 + t;
        if (i >= NN) return;
        int b = ld_idx(batch, i, fl[1]);
        int bp = (i == 0) ? -1 : ld_idx(batch, i - 1, fl[1]);
        for (int g = bp + 1; g <= b; g++)
            if ((unsigned)g <= NG) gstart[g] = i;
        if (i == NN - 1)
            for (int g = b + 1; g <= NG; g++) gstart[g] = NN;
    }
}

// ---------------- distributed scan: bucket sums | expand (bucket scan inline) -

__global__ __launch_bounds__(256) void k_scanA(const int* __restrict__ deg,
                                               int* __restrict__ bsum) {
    __shared__ int red[256];
    int t = threadIdx.x;
    int node = blockIdx.x * 256 + t;
    red[t] = (node < NN) ? deg[node] : 0;
    __syncthreads();
    for (int off = 128; off; off >>= 1) {
        if (t < off) red[t] += red[t + off];
        __syncthreads();
    }
    if (t == 0) bsum[blockIdx.x] = red[0];
}

__global__ __launch_bounds__(256) void k_scanC(
    const int* __restrict__ deg, const int* __restrict__ bsum,
    int* __restrict__ rowst, int* __restrict__ cursor, float* __restrict__ invdeg) {
    __shared__ int bpart[128];
    __shared__ int part[256];
    int b = blockIdx.x, t = threadIdx.x;
    // per-block scan of the 79 bucket sums (tiny)
    if (t < 128) {
        int s = (t < NBKT) ? bsum[t] : 0;
        bpart[t] = s;
    }
    __syncthreads();
    for (int off = 1; off < 128; off <<= 1) {
        int v = 0;
        if (t < 128 && t >= off) v = bpart[t - off];
        __syncthreads();
        if (t < 128) bpart[t] += v;
        __syncthreads();
    }
    int bpref = (b == 0) ? 0 : bpart[b - 1];   // exclusive prefix of this bucket
    if (b == 0 && t == 0) rowst[NN] = bpart[NBKT - 1];
    int node = b * 256 + t;
    int d = (node < NN) ? deg[node] : 0;
    part[t] = d;
    __syncthreads();
    for (int off = 1; off < 256; off <<= 1) {
        int v = (t >= off) ? part[t - off] : 0;
        __syncthreads();
        part[t] += v;
        __syncthreads();
    }
    if (node < NN) {
        int o = bpref + part[t] - d;
        rowst[node] = o;
        cursor[node] = o;
        invdeg[node] = d > 0 ? 1.0f / (float)d : 0.0f;
    }
}

__global__ void k_fill(const int* __restrict__ ei, int* __restrict__ cursor,
                       int* __restrict__ csr, const int* __restrict__ fl) {
    int e = blockIdx.x * 256 + threadIdx.x;
    if (e < NE) {
        int src = ld_idx(ei, e, fl[0]);
        int dst = ld_idx(ei, NE + e, fl[0]);
        if ((unsigned)dst < NN && (unsigned)src < NN) {
            int p = atomicAdd(&cursor[dst], 1);
            if ((unsigned)p < NE) csr[p] = src;
        }
    }
}

// ------- mean aggregation, column-sliced for L2 residency ---------------------
// grid (ceil(NN/4), 4): blockIdx.y = 64-col slice (2.5 MB of X -> fits XCD L2).
// wave = one node-slice; 8 edge-groups x 8 lanes x 16B = 8 edges per load issue.
// optional lazy BN+ReLU (BNF=1) applied to gathered elements in fp32.

template <int BNF>
__global__ __launch_bounds__(256) void k_agg5(
    const ushort* __restrict__ X, const int* __restrict__ rs,
    const int* __restrict__ csr, const float* __restrict__ invdeg,
    const float* __restrict__ bnsc, const float* __restrict__ bnsh,
    ushort* __restrict__ AGG) {
    int node = blockIdx.x * 4 + (threadIdx.x >> 6);
    if (node >= NN) return;
    int lane = threadIdx.x & 63;
    int g = lane >> 3;                 // edge group 0..7
    int j = lane & 7;                  // 16B chunk within the 128B slice
    int cb = blockIdx.y * 64 + j * 8;  // global col base for this lane's 8 elems
    float sc[8], sh[8];
    if (BNF) {
        float4 a0 = *(const float4*)(bnsc + cb);
        float4 a1 = *(const float4*)(bnsc + cb + 4);
        float4 b0 = *(const float4*)(bnsh + cb);
        float4 b1 = *(const float4*)(bnsh + cb + 4);
        sc[0] = a0.x; sc[1] = a0.y; sc[2] = a0.z; sc[3] = a0.w;
        sc[4] = a1.x; sc[5] = a1.y; sc[6] = a1.z; sc[7] = a1.w;
        sh[0] = b0.x; sh[1] = b0.y; sh[2] = b0.z; sh[3] = b0.w;
        sh[4] = b1.x; sh[5] = b1.y; sh[6] = b1.z; sh[7] = b1.w;
    }
    int e0 = rs[node], e1 = rs[node + 1];
    float acc[8] = {};
    int e = e0 + g;
    for (; e + 8 < e1; e += 16) {      // 2 independent loads in flight per lane
        int sA = csr[e], sB = csr[e + 8];
        int4 vA = *(const int4*)(X + (size_t)sA * DD + cb);
        int4 vB = *(const int4*)(X + (size_t)sB * DD + cb);
        const ushort* uA = (const ushort*)&vA;
        const ushort* uB = (const ushort*)&vB;
#pragma unroll
        for (int d = 0; d < 8; d++) {
            float xA = bf2f(uA[d]), xB = bf2f(uB[d]);
            if (BNF) {
                xA = fmaxf(xA * sc[d] + sh[d], 0.0f);
                xB = fmaxf(xB * sc[d] + sh[d], 0.0f);
            }
            acc[d] += xA + xB;
        }
    }
    for (; e < e1; e += 8) {
        int s = csr[e];
        int4 v = *(const int4*)(X + (size_t)s * DD + cb);
        const ushort* u = (const ushort*)&v;
#pragma unroll
        for (int d = 0; d < 8; d++) {
            float x = bf2f(u[d]);
            if (BNF) x = fmaxf(x * sc[d] + sh[d], 0.0f);
            acc[d] += x;
        }
    }
    // reduce across the 8 edge-groups (lane bits 3..5)
#pragma unroll
    for (int d = 0; d < 8; d++) {
        acc[d] += __shfl_xor(acc[d], 8);
        acc[d] += __shfl_xor(acc[d], 16);
        acc[d] += __shfl_xor(acc[d], 32);
    }
    if (g == 0) {
        float inv = invdeg[node];
        ushort ov[8];
#pragma unroll
        for (int d = 0; d < 8; d++) ov[d] = f2bf(acc[d] * inv);
        *(int4*)(AGG + (size_t)node * DD + cb) = *(int4*)ov;
    }
}

// ------- 128x128 GEMM: A via LDS, B via coalesced fragment loads from L2 ------

template <int BNF>
__global__ __launch_bounds__(256) void k_gemm5(
    const ushort* __restrict__ A1, const ushort* __restrict__ A2,
    const ushort* __restrict__ WtF1, const ushort* __restrict__ WtF2,
    const ushort* __restrict__ bias,
    const float* __restrict__ bnsc, const float* __restrict__ bnsh,
    ushort* __restrict__ H, float* __restrict__ psum, float* __restrict__ psq) {
    __shared__ ushort Als[128][40];
    __shared__ float colsum[128];
    __shared__ float colsq[128];
    const int m0 = blockIdx.x * 128;
    const int n0 = blockIdx.y * 128;
    const int tid = threadIdx.x;
    const int w = tid >> 6, l = tid & 63, lr = l & 15, q = l >> 4;
    const int wm = (w >> 1) * 64, wn = (w & 1) * 64;
    float4_t acc[4][4] = {};

    const int srow = tid >> 1;           // 0..127
    const int sce = (tid & 1) * 16;      // element offset (16 elems = 2 int4)
    const int nb8 = ((n0 + wn) >> 4) * 8;   // fragment block row for this wave

    for (int mat = 0; mat < 2; ++mat) {
        const ushort* A = mat ? A2 : A1;
        const ushort* Wf = mat ? WtF2 : WtF1;
        for (int k0 = 0; k0 < 256; k0 += 32) {
            int ar = m0 + srow; if (ar >= NN) ar = NN - 1;
            int4 av0 = *(const int4*)(A + (size_t)ar * DD + k0 + sce);
            int4 av1 = *(const int4*)(A + (size_t)ar * DD + k0 + sce + 8);
            if (BNF && mat == 1) {
                float scv[16], shv[16];
#pragma unroll
                for (int g = 0; g < 4; g++) {
                    float4 s4 = *(const float4*)(bnsc + k0 + sce + g * 4);
                    float4 h4 = *(const float4*)(bnsh + k0 + sce + g * 4);
                    scv[g*4] = s4.x; scv[g*4+1] = s4.y; scv[g*4+2] = s4.z; scv[g*4+3] = s4.w;
                    shv[g*4] = h4.x; shv[g*4+1] = h4.y; shv[g*4+2] = h4.z; shv[g*4+3] = h4.w;
                }
                ushort* u0 = (ushort*)&av0;
                ushort* u1 = (ushort*)&av1;
#pragma unroll
                for (int d = 0; d < 8; d++) {
                    u0[d] = f2bf(fmaxf(bf2f(u0[d]) * scv[d] + shv[d], 0.0f));
                    u1[d] = f2bf(fmaxf(bf2f(u1[d]) * scv[8 + d] + shv[8 + d], 0.0f));
                }
            }
            *(int4*)&Als[srow][sce] = av0;
            *(int4*)&Als[srow][sce + 8] = av1;
            // B fragments straight from global (L2-resident, coalesced lane*16B)
            const ushort* bbase = Wf + (((size_t)(nb8 + (k0 >> 5))) << 9) + l * 8;
            short8 bf[4];
#pragma unroll
            for (int in = 0; in < 4; in++)
                bf[in] = *(const short8*)(bbase + in * 4096);
            __syncthreads();
            short8 af[4];
#pragma unroll
            for (int im = 0; im < 4; im++)
                af[im] = *(const short8*)&Als[wm + im * 16 + lr][q * 8];
#pragma unroll
            for (int im = 0; im < 4; im++)
#pragma unroll
                for (int in = 0; in < 4; in++)
                    acc[im][in] = __builtin_amdgcn_mfma_f32_16x16x32_bf16(
                        af[im], bf[in], acc[im][in], 0, 0, 0);
            __syncthreads();
        }
    }
    if (tid < 128) { colsum[tid] = 0.0f; colsq[tid] = 0.0f; }
    __syncthreads();

    // epilogue: C/D layout col=lane&15, row=(lane>>4)*4+reg
    int mbase = m0 + wm + q * 4;
#pragma unroll
    for (int in = 0; in < 4; in++) {
        int n = n0 + wn + in * 16 + lr;
        float b = bf2f(bias[n]);
        float s = 0.0f, s2 = 0.0f;
#pragma unroll
        for (int im = 0; im < 4; im++) {
#pragma unroll
            for (int i = 0; i < 4; i++) {
                int m = mbase + im * 16 + i;
                if (m < NN) {
                    float hv = acc[im][in][i] + b;
                    ushort hb = f2bf(hv);
                    H[(size_t)m * DD + n] = hb;
                    float hq = bf2f(hb);
                    s += hq;
                    s2 += hq * hq;
                }
            }
        }
        s += __shfl_xor(s, 16);  s += __shfl_xor(s, 32);
        s2 += __shfl_xor(s2, 16); s2 += __shfl_xor(s2, 32);
        if (q == 0) {
            atomicAdd(&colsum[wn + in * 16 + lr], s);
            atomicAdd(&colsq[wn + in * 16 + lr], s2);
        }
    }
    __syncthreads();
    if (tid < 128) {
        psum[(size_t)blockIdx.x * DD + n0 + tid] = colsum[tid];
        psq[(size_t)blockIdx.x * DD + n0 + tid] = colsq[tid];
    }
}

// ---------------- BN finalize (separate dispatch; kernel boundary = release) --

__global__ __launch_bounds__(64) void k_bnfinal3(
    const float* __restrict__ psum, const float* __restrict__ psq,
    const ushort* __restrict__ gamma, const ushort* __restrict__ beta,
    float* __restrict__ scale, float* __restrict__ shift) {
    int c = blockIdx.x;     // 256
    int t = threadIdx.x;    // 64
    float s = 0.0f, s2 = 0.0f;
    for (int b = t; b < NBX2; b += 64) {
        s += psum[(size_t)b * DD + c];
        s2 += psq[(size_t)b * DD + c];
    }
#pragma unroll
    for (int o = 32; o; o >>= 1) {
        s += __shfl_down(s, o);
        s2 += __shfl_down(s2, o);
    }
    if (t == 0) {
        float mu = s * (1.0f / NN);
        float var = s2 * (1.0f / NN) - mu * mu;
        if (var < 0.0f) var = 0.0f;
        float rstd = rsqrtf(var + 1e-5f);
        float g = bf2f(gamma[c]);
        float b2 = bf2f(beta[c]);
        scale[c] = g * rstd;
        shift[c] = b2 - mu * g * rstd;
    }
}

// ---------------- fused pool (lazy BN) + MLP ----------------

__global__ __launch_bounds__(256) void k_head(
    const ushort* __restrict__ Hb, const float* __restrict__ scale,
    const float* __restrict__ shift, const int* __restrict__ gstart,
    const ushort* __restrict__ fc1w, const ushort* __restrict__ fc1b,
    const ushort* __restrict__ fc2w, const ushort* __restrict__ fc2b,
    const ushort* __restrict__ fc3w, const ushort* __restrict__ fc3b,
    void* __restrict__ out, const int* __restrict__ fl) {
    __shared__ float g[256];
    __shared__ float h1[128];
    __shared__ float h2[64];
    int gid = blockIdx.x;
    int t = threadIdx.x;
    int s0 = gstart[gid], e = gstart[gid + 1];
    float sc = scale[t], sh = shift[t];
    float acc = 0.0f;
    for (int i = s0; i < e; i++)
        acc += fmaxf(bf2f(Hb[(size_t)i * DD + t]) * sc + sh, 0.0f);
    g[t] = acc / fmaxf((float)(e - s0), 1.0f);
    __syncthreads();
    if (t < 128) {
        float a = bf2f(fc1b[t]);
        for (int k = 0; k < 256; k++)
            a += g[k] * bf2f(fc1w[k * 128 + t]);
        h1[t] = fmaxf(a, 0.0f);
    }
    __syncthreads();
    if (t < 64) {
        float a2 = bf2f(fc2b[t]);
        for (int k = 0; k < 128; k++)
            a2 += h1[k] * bf2f(fc2w[k * 64 + t]);
        h2[t] = fmaxf(a2, 0.0f);
    }
    __syncthreads();
    if (t < 10) {
        float a3 = bf2f(fc3b[t]);
        for (int k = 0; k < 64; k++)
            a3 += h2[k] * bf2f(fc3w[k * 10 + t]);
        if (fl[2]) ((__hip_bfloat16*)out)[gid * 10 + t] = __float2bfloat16(a3);
        else       ((float*)out)[gid * 10 + t] = a3;
    }
}

// ---------------- host ----------------

static inline char* bump(char*& p, size_t n) {
    char* r = p;
    p += (n + 255) & ~(size_t)255;
    return r;
}

extern "C" void kernel_launch(void* const* d_in, const int* in_sizes, int n_in,
                              void* d_out, int out_size, void* d_ws, size_t ws_size,
                              hipStream_t stream) {
    const void* x_in  = d_in[0];
    const int*  ei    = (const int*)d_in[1];
    const int*  batch = (const int*)d_in[2];
    const void* Wl    = d_in[3];
    const void* bl    = d_in[4];
    const void* Wr    = d_in[5];
    const void* gamma = d_in[6];
    const void* beta  = d_in[7];

    char* p = (char*)d_ws;
    int*    flags    = (int*)bump(p, 256);
    ushort* wtL      = (ushort*)bump(p, (size_t)NL * 65536 * 2);   // fragment layout
    ushort* wtR      = (ushort*)bump(p, (size_t)NL * 65536 * 2);   // fragment layout
    ushort* xcan     = (ushort*)bump(p, (size_t)NN * DD * 2);
    ushort* pcan     = (ushort*)bump(p, (size_t)PTOT * 2);
    int*    deg      = (int*)bump(p, NN * 4);
    int*    bsum     = (int*)bump(p, NBKT * 4);
    int*    rowst    = (int*)bump(p, (NN + 1) * 4);
    int*    cursor   = (int*)bump(p, NN * 4);
    float*  invdeg   = (float*)bump(p, NN * 4);
    int*    csr      = (int*)bump(p, NE * 4);
    int*    gstart   = (int*)bump(p, (NG + 1) * 4);
    ushort* agg      = (ushort*)bump(p, (size_t)NN * DD * 2);
    ushort* hb0      = (ushort*)bump(p, (size_t)NN * DD * 2);
    ushort* hb1      = (ushort*)bump(p, (size_t)NN * DD * 2);
    float*  psum     = (float*)bump(p, (size_t)NBX2 * DD * 4);
    float*  psq      = (float*)bump(p, (size_t)NBX2 * DD * 4);
    float*  scale    = (float*)bump(p, DD * 4);
    float*  shift    = (float*)bump(p, DD * 4);

    if ((size_t)(p - (char*)d_ws) > ws_size) return;

    ushort* blc = pcan + POFF_BL;
    ushort* gac = pcan + POFF_GA;
    ushort* bec = pcan + POFF_BE;
    ushort* f1w = pcan + POFF_F1W;
    ushort* f1b = pcan + POFF_F1B;
    ushort* f2w = pcan + POFF_F2W;
    ushort* f2b = pcan + POFF_F2B;
    ushort* f3w = pcan + POFF_F3W;
    ushort* f3b = pcan + POFF_F3B;

    k_init<<<80, 256, 0, stream>>>(ei, batch, (const ushort*)x_in, flags, deg);
    k_prep<<<NB_PREP, 256, 0, stream>>>(
        x_in, Wl, Wr, ei, batch,
        bl, gamma, beta, d_in[8], d_in[9], d_in[10], d_in[11], d_in[12], d_in[13],
        xcan, wtL, wtR, pcan, deg, gstart, flags);
    k_scanA<<<NBKT, 256, 0, stream>>>(deg, bsum);
    k_scanC<<<NBKT, 256, 0, stream>>>(deg, bsum, rowst, cursor, invdeg);
    k_fill<<<(NE + 255) / 256, 256, 0, stream>>>(ei, cursor, csr, flags);

    ushort* hbuf[2] = {hb0, hb1};
    const ushort* xsrc = xcan;
    for (int l = 0; l < NL; l++) {
        ushort* hdst = hbuf[l & 1];
        if (l == 0) {
            k_agg5<0><<<dim3((NN + 3) / 4, 4), 256, 0, stream>>>(
                xsrc, rowst, csr, invdeg, scale, shift, agg);
            k_gemm5<0><<<dim3(NBX2, 2), 256, 0, stream>>>(
                agg, xsrc, wtL, wtR, blc, scale, shift, hdst, psum, psq);
        } else {
            k_agg5<1><<<dim3((NN + 3) / 4, 4), 256, 0, stream>>>(
                xsrc, rowst, csr, invdeg, scale, shift, agg);
            k_gemm5<1><<<dim3(NBX2, 2), 256, 0, stream>>>(
                agg, xsrc, wtL + (size_t)l * 65536, wtR + (size_t)l * 65536,
                blc + l * DD, scale, shift, hdst, psum, psq);
        }
        k_bnfinal3<<<DD, 64, 0, stream>>>(psum, psq, gac + l * DD, bec + l * DD,
                                          scale, shift);
        xsrc = hdst;
    }

    k_head<<<NG, 256, 0, stream>>>(xsrc, scale, shift, gstart,
                                   f1w, f1b, f2w, f2b, f3w, f3b, d_out, flags);
}

// Round 12
// 371.127 us; speedup vs baseline: 1.0726x; 1.0726x over previous
//
#include <hip/hip_runtime.h>
#include <hip/hip_bf16.h>

#define NN 20000
#define NE 320000
#define NG 256
#define DD 256
#define NL 4
#define NBX2 157   // (NN+127)/128 gemm m-blocks
#define NBKT 79    // ceil(NN/256) scan buckets

typedef __attribute__((ext_vector_type(8))) short short8;
typedef __attribute__((ext_vector_type(4))) float float4_t;

// flags[0]=1 if edge_index int64; flags[1]=1 if batch int64; flags[2]=1 if floats bf16
__device__ __forceinline__ int ld_idx(const int* __restrict__ p, int i, int f64) {
    return f64 ? p[2 * i] : p[i];
}

__device__ __forceinline__ float bf2f(ushort u) {
    return __uint_as_float(((unsigned)u) << 16);
}

__device__ __forceinline__ ushort f2bf(float f) {
    __hip_bfloat16 b = __float2bfloat16(f);
    return *(ushort*)&b;
}

// ---------------- init: zero deg, dtype detection (block 0) ----

__global__ void k_init(const int* __restrict__ ei, const int* __restrict__ batch,
                       const ushort* __restrict__ x, int* __restrict__ flags,
                       int* __restrict__ deg) {
    int gid = blockIdx.x * 256 + threadIdx.x;
    for (int i = gid; i < NN; i += gridDim.x * 256) deg[i] = 0;
    if (blockIdx.x == 0) {
        __shared__ int cnt0, cnt1, weird;
        int t = threadIdx.x;
        if (t == 0) { cnt0 = 0; cnt1 = 0; weird = 0; }
        __syncthreads();
        for (int tt = t; tt < 512; tt += 256) {
            if (ei[2 * tt + 1] != 0) atomicAdd(&cnt0, 1);
            int i = tt * 9;
            if (batch[2 * i + 1] != 0) atomicAdd(&cnt1, 1);
#pragma unroll
            for (int j = 0; j < 16; j++) {
                ushort v = x[tt * 16 + j];
                if (((v >> 7) & 0xFF) >= 0xC0) atomicAdd(&weird, 1);
            }
        }
        __syncthreads();
        if (t == 0) {
            flags[0] = (cnt0 == 0) ? 1 : 0;
            flags[1] = (cnt1 == 0) ? 1 : 0;
            flags[2] = (weird == 0) ? 1 : 0;
        }
    }
}

// ---------------- fused prep: cvt8 | WtF frag-build(tiled) | cvtp | degree | gstart

#define POFF_BL   0
#define POFF_GA   1024
#define POFF_BE   2048
#define POFF_F1W  3072
#define POFF_F1B  35840
#define POFF_F2W  35968
#define POFF_F2B  44160
#define POFF_F3W  44224
#define POFF_F3B  44864
#define PTOT      44874

#define NB_CVT8   2500            // NN*DD/8/256
#define NB_FRAG   128             // 8 matrices x 16 (64x64) tiles
#define NB_CVTP   176             // ceil(PTOT/256)
#define NB_DEG    1250            // NE/256
#define NB_GST    79              // ceil(NN/256)
#define B_FRAG    (NB_CVT8)
#define B_CVTP    (B_FRAG + NB_FRAG)
#define B_DEG     (B_CVTP + NB_CVTP)
#define B_GST     (B_DEG + NB_DEG)
#define NB_PREP   (B_GST + NB_GST)

// WtF fragment layout (per 256x256 matrix, 65536 elems):
//   element (n,k) lives at  ((n>>4)*8 + (k>>5))*512 + ((n&15) + 16*((k>>3)&3))*8 + (k&7)
// so a wave's B-fragment load is base + lane*8 (lane-contiguous 16B -> coalesced).

__global__ __launch_bounds__(256) void k_prep(
    const void* __restrict__ x_in, const void* __restrict__ WL,
    const void* __restrict__ WR, const int* __restrict__ ei,
    const int* __restrict__ batch,
    const void* s0, const void* s1, const void* s2, const void* s3,
    const void* s4, const void* s5, const void* s6, const void* s7, const void* s8,
    ushort* __restrict__ xcan, ushort* __restrict__ wtL, ushort* __restrict__ wtR,
    ushort* __restrict__ pcan, int* __restrict__ deg, int* __restrict__ gstart,
    const int* __restrict__ fl) {
    int blk = blockIdx.x;
    int t = threadIdx.x;
    if (blk < B_FRAG) {
        // x canonicalization, 8 elems/lane
        int i = blk * 256 + t;
        if (fl[2]) {
            *(int4*)(xcan + (size_t)i * 8) = ((const int4*)x_in)[i];
        } else {
            const float* f = (const float*)x_in + (size_t)i * 8;
            ushort ov[8];
#pragma unroll
            for (int d = 0; d < 8; d++) ov[d] = f2bf(f[d]);
            *(int4*)(xcan + (size_t)i * 8) = *(int4*)ov;
        }
    } else if (blk < B_CVTP) {
        // tiled B-fragment build: LDS transpose, coalesced in and out
        __shared__ ushort T[64][65];   // T[n_local][k_local]
        int bid = blk - B_FRAG;        // 0..127
        int lm = bid >> 4;             // 0..7 (0-3: L, 4-7: R)
        int tile = bid & 15;
        int tk = (tile >> 2) * 64, tn = (tile & 3) * 64;
        const void* W = (lm >= 4) ? WR : WL;
        ushort* Wt = (lm >= 4) ? wtR : wtL;
        size_t base = (size_t)(lm & 3) << 16;
        int f32 = !fl[2];
#pragma unroll
        for (int i = 0; i < 16; i++) {
            int flat = t + i * 256;
            int r = flat >> 6, c = flat & 63;   // read W[tk+r][tn+c], coalesced in c
            size_t src = base + (size_t)(tk + r) * 256 + tn + c;
            ushort v = f32 ? f2bf(((const float*)W)[src]) : ((const ushort*)W)[src];
            T[c][r] = v;
        }
        __syncthreads();
        // write 16B/thread in fragment order (coalesced)
#pragma unroll
        for (int i = 0; i < 2; i++) {
            int slot = t + i * 256;            // 0..511
            int f = slot >> 6;                 // local fblk 0..7
            int lane = slot & 63;
            int ln = (f >> 1) * 16 + (lane & 15);
            int lk = (f & 1) * 32 + ((lane >> 4) << 3);
            int gfblk = ((tn + ln) >> 4) * 8 + ((tk + lk) >> 5);
            ushort tmp[8];
#pragma unroll
            for (int j = 0; j < 8; j++) tmp[j] = T[ln][lk + j];
            *(int4*)(Wt + base + (size_t)gfblk * 512 + lane * 8) = *(int4*)tmp;
        }
    } else if (blk < B_DEG) {
        // small params
        int i = (blk - B_CVTP) * 256 + t;
        if (i >= PTOT) return;
        const int offs[10] = {POFF_BL, POFF_GA, POFF_BE, POFF_F1W, POFF_F1B,
                              POFF_F2W, POFF_F2B, POFF_F3W, POFF_F3B, PTOT};
        const void* srcs[9] = {s0, s1, s2, s3, s4, s5, s6, s7, s8};
        int seg = 0;
#pragma unroll
        for (int k = 1; k < 9; k++) if (i >= offs[k]) seg = k;
        int local = i - offs[seg];
        if (fl[2]) pcan[i] = ((const ushort*)srcs[seg])[local];
        else       pcan[i] = f2bf(((const float*)srcs[seg])[local]);
    } else if (blk < B_GST) {
        // degree
        int e = (blk - B_DEG) * 256 + t;
        if (e < NE) {
            int src = ld_idx(ei, e, fl[0]);
            int dst = ld_idx(ei, NE + e, fl[0]);
            if ((unsigned)dst < NN && (unsigned)src < NN) atomicAdd(&deg[dst], 1);
        }
    } else {
        // gstart
        int i = (blk - B_GST) * 256 + t;
        if (i >= NN) return;
        int b = ld_idx(batch, i, fl[1]);
        int bp = (i == 0) ? -1 : ld_idx(batch, i - 1, fl[1]);
        for (int g = bp + 1; g <= b; g++)
            if ((unsigned)g <= NG) gstart[g] = i;
        if (i == NN - 1)
            for (int g = b + 1; g <= NG; g++) gstart[g] = NN;
    }
}

// ---------------- distributed scan: bucket sums | expand (bucket scan inline) -

__global__ __launch_bounds__(256) void k_scanA(const int* __restrict__ deg,
                                               int* __restrict__ bsum) {
    __shared__ int red[256];
    int t = threadIdx.x;
    int node = blockIdx.x * 256 + t;
    red[t] = (node < NN) ? deg[node] : 0;
    __syncthreads();
    for (int off = 128; off; off >>= 1) {
        if (t < off) red[t] += red[t + off];
        __syncthreads();
    }
    if (t == 0) bsum[blockIdx.x] = red[0];
}

__global__ __launch_bounds__(256) void k_scanC(
    const int* __restrict__ deg, const int* __restrict__ bsum,
    int* __restrict__ rowst, int* __restrict__ cursor, float* __restrict__ invdeg) {
    __shared__ int bpart[128];
    __shared__ int part[256];
    int b = blockIdx.x, t = threadIdx.x;
    if (t < 128) {
        int s = (t < NBKT) ? bsum[t] : 0;
        bpart[t] = s;
    }
    __syncthreads();
    for (int off = 1; off < 128; off <<= 1) {
        int v = 0;
        if (t < 128 && t >= off) v = bpart[t - off];
        __syncthreads();
        if (t < 128) bpart[t] += v;
        __syncthreads();
    }
    int bpref = (b == 0) ? 0 : bpart[b - 1];
    if (b == 0 && t == 0) rowst[NN] = bpart[NBKT - 1];
    int node = b * 256 + t;
    int d = (node < NN) ? deg[node] : 0;
    part[t] = d;
    __syncthreads();
    for (int off = 1; off < 256; off <<= 1) {
        int v = (t >= off) ? part[t - off] : 0;
        __syncthreads();
        part[t] += v;
        __syncthreads();
    }
    if (node < NN) {
        int o = bpref + part[t] - d;
        rowst[node] = o;
        cursor[node] = o;
        invdeg[node] = d > 0 ? 1.0f / (float)d : 0.0f;
    }
}

__global__ void k_fill(const int* __restrict__ ei, int* __restrict__ cursor,
                       int* __restrict__ csr, const int* __restrict__ fl) {
    int e = blockIdx.x * 256 + threadIdx.x;
    if (e < NE) {
        int src = ld_idx(ei, e, fl[0]);
        int dst = ld_idx(ei, NE + e, fl[0]);
        if ((unsigned)dst < NN && (unsigned)src < NN) {
            int p = atomicAdd(&cursor[dst], 1);
            if ((unsigned)p < NE) csr[p] = src;
        }
    }
}

// ------- mean aggregation, ILP-8, optional lazy BN+ReLU on gathered rows -----

template <int BNF>
__global__ __launch_bounds__(256) void k_agg4(
    const ushort* __restrict__ X, const int* __restrict__ rs,
    const int* __restrict__ csr, const float* __restrict__ invdeg,
    const float* __restrict__ bnsc, const float* __restrict__ bnsh,
    ushort* __restrict__ AGG) {
    int node = blockIdx.x * 4 + (threadIdx.x >> 6);
    if (node >= NN) return;
    int h = (threadIdx.x >> 5) & 1;   // half-wave: edges e0+h, e0+h+2, ...
    int j = threadIdx.x & 31;         // dims j*8..j*8+7
    float sc[8], sh[8];
    if (BNF) {
        float4 a0 = *(const float4*)(bnsc + j * 8);
        float4 a1 = *(const float4*)(bnsc + j * 8 + 4);
        float4 b0 = *(const float4*)(bnsh + j * 8);
        float4 b1 = *(const float4*)(bnsh + j * 8 + 4);
        sc[0] = a0.x; sc[1] = a0.y; sc[2] = a0.z; sc[3] = a0.w;
        sc[4] = a1.x; sc[5] = a1.y; sc[6] = a1.z; sc[7] = a1.w;
        sh[0] = b0.x; sh[1] = b0.y; sh[2] = b0.z; sh[3] = b0.w;
        sh[4] = b1.x; sh[5] = b1.y; sh[6] = b1.z; sh[7] = b1.w;
    }
    int e0 = rs[node], e1 = rs[node + 1];
    float acc[8] = {};
    int e = e0 + h;
    for (; e + 14 < e1; e += 16) {     // 8 independent row loads in flight
        int4 v[8];
#pragma unroll
        for (int r = 0; r < 8; r++) {
            int s = csr[e + 2 * r];
            v[r] = *(const int4*)(X + (size_t)s * DD + j * 8);
        }
#pragma unroll
        for (int r = 0; r < 8; r++) {
            const ushort* u = (const ushort*)&v[r];
#pragma unroll
            for (int d = 0; d < 8; d++) {
                float x = bf2f(u[d]);
                if (BNF) x = fmaxf(x * sc[d] + sh[d], 0.0f);
                acc[d] += x;
            }
        }
    }
    for (; e + 2 < e1; e += 4) {       // pairs
        int sA = csr[e], sB = csr[e + 2];
        int4 vA = *(const int4*)(X + (size_t)sA * DD + j * 8);
        int4 vB = *(const int4*)(X + (size_t)sB * DD + j * 8);
        const ushort* uA = (const ushort*)&vA;
        const ushort* uB = (const ushort*)&vB;
#pragma unroll
        for (int d = 0; d < 8; d++) {
            float xA = bf2f(uA[d]), xB = bf2f(uB[d]);
            if (BNF) {
                xA = fmaxf(xA * sc[d] + sh[d], 0.0f);
                xB = fmaxf(xB * sc[d] + sh[d], 0.0f);
            }
            acc[d] += xA + xB;
        }
    }
    for (; e < e1; e += 2) {
        int s = csr[e];
        int4 v = *(const int4*)(X + (size_t)s * DD + j * 8);
        const ushort* u = (const ushort*)&v;
#pragma unroll
        for (int d = 0; d < 8; d++) {
            float x = bf2f(u[d]);
            if (BNF) x = fmaxf(x * sc[d] + sh[d], 0.0f);
            acc[d] += x;
        }
    }
#pragma unroll
    for (int d = 0; d < 8; d++)
        acc[d] += __shfl_down(acc[d], 32);
    if (h == 0) {
        float inv = invdeg[node];
        ushort ov[8];
#pragma unroll
        for (int d = 0; d < 8; d++) ov[d] = f2bf(acc[d] * inv);
        *(int4*)(AGG + (size_t)node * DD + j * 8) = *(int4*)ov;
    }
}

// ------- 128x128 GEMM: A via LDS, B via coalesced fragment loads from L2 ------

template <int BNF>
__global__ __launch_bounds__(256) void k_gemm5(
    const ushort* __restrict__ A1, const ushort* __restrict__ A2,
    const ushort* __restrict__ WtF1, const ushort* __restrict__ WtF2,
    const ushort* __restrict__ bias,
    const float* __restrict__ bnsc, const float* __restrict__ bnsh,
    ushort* __restrict__ H, float* __restrict__ psum, float* __restrict__ psq) {
    __shared__ ushort Als[128][40];
    __shared__ float colsum[128];
    __shared__ float colsq[128];
    const int m0 = blockIdx.x * 128;
    const int n0 = blockIdx.y * 128;
    const int tid = threadIdx.x;
    const int w = tid >> 6, l = tid & 63, lr = l & 15, q = l >> 4;
    const int wm = (w >> 1) * 64, wn = (w & 1) * 64;
    float4_t acc[4][4] = {};

    const int srow = tid >> 1;           // 0..127
    const int sce = (tid & 1) * 16;      // element offset (16 elems = 2 int4)
    const int nb8 = ((n0 + wn) >> 4) * 8;   // fragment block row for this wave

    for (int mat = 0; mat < 2; ++mat) {
        const ushort* A = mat ? A2 : A1;
        const ushort* Wf = mat ? WtF2 : WtF1;
        for (int k0 = 0; k0 < 256; k0 += 32) {
            int ar = m0 + srow; if (ar >= NN) ar = NN - 1;
            int4 av0 = *(const int4*)(A + (size_t)ar * DD + k0 + sce);
            int4 av1 = *(const int4*)(A + (size_t)ar * DD + k0 + sce + 8);
            if (BNF && mat == 1) {
                float scv[16], shv[16];
#pragma unroll
                for (int g = 0; g < 4; g++) {
                    float4 s4 = *(const float4*)(bnsc + k0 + sce + g * 4);
                    float4 h4 = *(const float4*)(bnsh + k0 + sce + g * 4);
                    scv[g*4] = s4.x; scv[g*4+1] = s4.y; scv[g*4+2] = s4.z; scv[g*4+3] = s4.w;
                    shv[g*4] = h4.x; shv[g*4+1] = h4.y; shv[g*4+2] = h4.z; shv[g*4+3] = h4.w;
                }
                ushort* u0 = (ushort*)&av0;
                ushort* u1 = (ushort*)&av1;
#pragma unroll
                for (int d = 0; d < 8; d++) {
                    u0[d] = f2bf(fmaxf(bf2f(u0[d]) * scv[d] + shv[d], 0.0f));
                    u1[d] = f2bf(fmaxf(bf2f(u1[d]) * scv[8 + d] + shv[8 + d], 0.0f));
                }
            }
            *(int4*)&Als[srow][sce] = av0;
            *(int4*)&Als[srow][sce + 8] = av1;
            // B fragments straight from global (L2-resident, coalesced lane*16B)
            const ushort* bbase = Wf + (((size_t)(nb8 + (k0 >> 5))) << 9) + l * 8;
            short8 bf[4];
#pragma unroll
            for (int in = 0; in < 4; in++)
                bf[in] = *(const short8*)(bbase + in * 4096);
            __syncthreads();
            short8 af[4];
#pragma unroll
            for (int im = 0; im < 4; im++)
                af[im] = *(const short8*)&Als[wm + im * 16 + lr][q * 8];
#pragma unroll
            for (int im = 0; im < 4; im++)
#pragma unroll
                for (int in = 0; in < 4; in++)
                    acc[im][in] = __builtin_amdgcn_mfma_f32_16x16x32_bf16(
                        af[im], bf[in], acc[im][in], 0, 0, 0);
            __syncthreads();
        }
    }
    if (tid < 128) { colsum[tid] = 0.0f; colsq[tid] = 0.0f; }
    __syncthreads();

    // epilogue: C/D layout col=lane&15, row=(lane>>4)*4+reg
    int mbase = m0 + wm + q * 4;
#pragma unroll
    for (int in = 0; in < 4; in++) {
        int n = n0 + wn + in * 16 + lr;
        float b = bf2f(bias[n]);
        float s = 0.0f, s2 = 0.0f;
#pragma unroll
        for (int im = 0; im < 4; im++) {
#pragma unroll
            for (int i = 0; i < 4; i++) {
                int m = mbase + im * 16 + i;
                if (m < NN) {
                    float hv = acc[im][in][i] + b;
                    ushort hb = f2bf(hv);
                    H[(size_t)m * DD + n] = hb;
                    float hq = bf2f(hb);
                    s += hq;
                    s2 += hq * hq;
                }
            }
        }
        s += __shfl_xor(s, 16);  s += __shfl_xor(s, 32);
        s2 += __shfl_xor(s2, 16); s2 += __shfl_xor(s2, 32);
        if (q == 0) {
            atomicAdd(&colsum[wn + in * 16 + lr], s);
            atomicAdd(&colsq[wn + in * 16 + lr], s2);
        }
    }
    __syncthreads();
    if (tid < 128) {
        psum[(size_t)blockIdx.x * DD + n0 + tid] = colsum[tid];
        psq[(size_t)blockIdx.x * DD + n0 + tid] = colsq[tid];
    }
}

// ---------------- BN finalize (separate dispatch; kernel boundary = release) --

__global__ __launch_bounds__(64) void k_bnfinal3(
    const float* __restrict__ psum, const float* __restrict__ psq,
    const ushort* __restrict__ gamma, const ushort* __restrict__ beta,
    float* __restrict__ scale, float* __restrict__ shift) {
    int c = blockIdx.x;     // 256
    int t = threadIdx.x;    // 64
    float s = 0.0f, s2 = 0.0f;
    for (int b = t; b < NBX2; b += 64) {
        s += psum[(size_t)b * DD + c];
        s2 += psq[(size_t)b * DD + c];
    }
#pragma unroll
    for (int o = 32; o; o >>= 1) {
        s += __shfl_down(s, o);
        s2 += __shfl_down(s2, o);
    }
    if (t == 0) {
        float mu = s * (1.0f / NN);
        float var = s2 * (1.0f / NN) - mu * mu;
        if (var < 0.0f) var = 0.0f;
        float rstd = rsqrtf(var + 1e-5f);
        float g = bf2f(gamma[c]);
        float b2 = bf2f(beta[c]);
        scale[c] = g * rstd;
        shift[c] = b2 - mu * g * rstd;
    }
}

// ---------------- fused pool (lazy BN) + MLP ----------------

__global__ __launch_bounds__(256) void k_head(
    const ushort* __restrict__ Hb, const float* __restrict__ scale,
    const float* __restrict__ shift, const int* __restrict__ gstart,
    const ushort* __restrict__ fc1w, const ushort* __restrict__ fc1b,
    const ushort* __restrict__ fc2w, const ushort* __restrict__ fc2b,
    const ushort* __restrict__ fc3w, const ushort* __restrict__ fc3b,
    void* __restrict__ out, const int* __restrict__ fl) {
    __shared__ float g[256];
    __shared__ float h1[128];
    __shared__ float h2[64];
    int gid = blockIdx.x;
    int t = threadIdx.x;
    int s0 = gstart[gid], e = gstart[gid + 1];
    float sc = scale[t], sh = shift[t];
    float acc = 0.0f;
    for (int i = s0; i < e; i++)
        acc += fmaxf(bf2f(Hb[(size_t)i * DD + t]) * sc + sh, 0.0f);
    g[t] = acc / fmaxf((float)(e - s0), 1.0f);
    __syncthreads();
    if (t < 128) {
        float a = bf2f(fc1b[t]);
        for (int k = 0; k < 256; k++)
            a += g[k] * bf2f(fc1w[k * 128 + t]);
        h1[t] = fmaxf(a, 0.0f);
    }
    __syncthreads();
    if (t < 64) {
        float a2 = bf2f(fc2b[t]);
        for (int k = 0; k < 128; k++)
            a2 += h1[k] * bf2f(fc2w[k * 64 + t]);
        h2[t] = fmaxf(a2, 0.0f);
    }
    __syncthreads();
    if (t < 10) {
        float a3 = bf2f(fc3b[t]);
        for (int k = 0; k < 64; k++)
            a3 += h2[k] * bf2f(fc3w[k * 10 + t]);
        if (fl[2]) ((__hip_bfloat16*)out)[gid * 10 + t] = __float2bfloat16(a3);
        else       ((float*)out)[gid * 10 + t] = a3;
    }
}

// ---------------- host ----------------

static inline char* bump(char*& p, size_t n) {
    char* r = p;
    p += (n + 255) & ~(size_t)255;
    return r;
}

extern "C" void kernel_launch(void* const* d_in, const int* in_sizes, int n_in,
                              void* d_out, int out_size, void* d_ws, size_t ws_size,
                              hipStream_t stream) {
    const void* x_in  = d_in[0];
    const int*  ei    = (const int*)d_in[1];
    const int*  batch = (const int*)d_in[2];
    const void* Wl    = d_in[3];
    const void* bl    = d_in[4];
    const void* Wr    = d_in[5];
    const void* gamma = d_in[6];
    const void* beta  = d_in[7];

    char* p = (char*)d_ws;
    int*    flags    = (int*)bump(p, 256);
    ushort* wtL      = (ushort*)bump(p, (size_t)NL * 65536 * 2);   // fragment layout
    ushort* wtR      = (ushort*)bump(p, (size_t)NL * 65536 * 2);   // fragment layout
    ushort* xcan     = (ushort*)bump(p, (size_t)NN * DD * 2);
    ushort* pcan     = (ushort*)bump(p, (size_t)PTOT * 2);
    int*    deg      = (int*)bump(p, NN * 4);
    int*    bsum     = (int*)bump(p, NBKT * 4);
    int*    rowst    = (int*)bump(p, (NN + 1) * 4);
    int*    cursor   = (int*)bump(p, NN * 4);
    float*  invdeg   = (float*)bump(p, NN * 4);
    int*    csr      = (int*)bump(p, NE * 4);
    int*    gstart   = (int*)bump(p, (NG + 1) * 4);
    ushort* agg      = (ushort*)bump(p, (size_t)NN * DD * 2);
    ushort* hb0      = (ushort*)bump(p, (size_t)NN * DD * 2);
    ushort* hb1      = (ushort*)bump(p, (size_t)NN * DD * 2);
    float*  psum     = (float*)bump(p, (size_t)NBX2 * DD * 4);
    float*  psq      = (float*)bump(p, (size_t)NBX2 * DD * 4);
    float*  scale    = (float*)bump(p, DD * 4);
    float*  shift    = (float*)bump(p, DD * 4);

    if ((size_t)(p - (char*)d_ws) > ws_size) return;

    ushort* blc = pcan + POFF_BL;
    ushort* gac = pcan + POFF_GA;
    ushort* bec = pcan + POFF_BE;
    ushort* f1w = pcan + POFF_F1W;
    ushort* f1b = pcan + POFF_F1B;
    ushort* f2w = pcan + POFF_F2W;
    ushort* f2b = pcan + POFF_F2B;
    ushort* f3w = pcan + POFF_F3W;
    ushort* f3b = pcan + POFF_F3B;

    k_init<<<80, 256, 0, stream>>>(ei, batch, (const ushort*)x_in, flags, deg);
    k_prep<<<NB_PREP, 256, 0, stream>>>(
        x_in, Wl, Wr, ei, batch,
        bl, gamma, beta, d_in[8], d_in[9], d_in[10], d_in[11], d_in[12], d_in[13],
        xcan, wtL, wtR, pcan, deg, gstart, flags);
    k_scanA<<<NBKT, 256, 0, stream>>>(deg, bsum);
    k_scanC<<<NBKT, 256, 0, stream>>>(deg, bsum, rowst, cursor, invdeg);
    k_fill<<<(NE + 255) / 256, 256, 0, stream>>>(ei, cursor, csr, flags);

    ushort* hbuf[2] = {hb0, hb1};
    const ushort* xsrc = xcan;
    for (int l = 0; l < NL; l++) {
        ushort* hdst = hbuf[l & 1];
        if (l == 0) {
            k_agg4<0><<<(NN + 3) / 4, 256, 0, stream>>>(xsrc, rowst, csr, invdeg,
                                                        scale, shift, agg);
            k_gemm5<0><<<dim3(NBX2, 2), 256, 0, stream>>>(
                agg, xsrc, wtL, wtR, blc, scale, shift, hdst, psum, psq);
        } else {
            k_agg4<1><<<(NN + 3) / 4, 256, 0, stream>>>(xsrc, rowst, csr, invdeg,
                                                        scale, shift, agg);
            k_gemm5<1><<<dim3(NBX2, 2), 256, 0, stream>>>(
                agg, xsrc, wtL + (size_t)l * 65536, wtR + (size_t)l * 65536,
                blc + l * DD, scale, shift, hdst, psum, psq);
        }
        k_bnfinal3<<<DD, 64, 0, stream>>>(psum, psq, gac + l * DD, bec + l * DD,
                                          scale, shift);
        xsrc = hdst;
    }

    k_head<<<NG, 256, 0, stream>>>(xsrc, scale, shift, gstart,
                                   f1w, f1b, f2w, f2b, f3w, f3b, d_out, flags);
}